// Round 6
// baseline (194.371 us; speedup 1.0000x reference)
//
#include <hip/hip_runtime.h>

// ConvCaps via MFMA: per block (b, ho, 8 wo), votes = W[256 oc x 144 k] *
// X_im2col[144 k x 64 n], n = p*8+ci, k = (kh*3+kw)*16 + pi (padded to 160).
// mfma_f32_16x16x32_f16, fp32 accumulate. Prep kernel writes fp16 A-frags
// (80 KB) to d_ws once per call; all blocks stream them from L2.
// No materialized B tile: since k0 = kt*32+g*8 is 0 or 8 mod 16, a B-frag's
// 8 k's share one (kh,kw); the frag = 4 h2's of one xs row at stride RS ->
// 4x ds_read_b32 (ci-padded xs rows -> conflict-free).
// Routing runs in MFMA C-layout: lane=(p,ci), regs=[co=m][po=g*4+r].
//   ci-sum   : DPP quad_perm xor1 (0xB1), xor2 (0x4E), row xor7-rotate (0x141)
//   po-sum   : ds_swizzle xor16 (0x401F) + __shfl_xor 32
//   softmax  : 1024 items over 256 threads, DPP row_ror reduces
// bb stride 17 (16 writer lanes -> 16 banks). vjlds unions with dead xs.

namespace {
constexpr int CI = 8, PIn = 16, H = 64, Wd = 64;
constexpr int TP = 8;          // wo pixels per block
constexpr int NQ = 8;          // pi pairs in x patch
constexpr int RS = 24;         // halfs per (r,q) patch row (20 used)
constexpr int PADH = 8;        // per-ci pad in halfs (bank decorrelation)
constexpr int XCIS = 3 * NQ * RS + PADH;   // 584 halfs per ci
constexpr int KT = 5;          // K tiles of 32 (K=160, 144 real)
}

typedef __fp16 h2  __attribute__((ext_vector_type(2)));
typedef __fp16 f16x8 __attribute__((ext_vector_type(8)));
typedef float  f32x4 __attribute__((ext_vector_type(4)));

__device__ __forceinline__ h2 pkh(float a, float b) {
#if __has_builtin(__builtin_amdgcn_cvt_pkrtz)
    return __builtin_amdgcn_cvt_pkrtz(a, b);
#else
    h2 r; r[0] = (__fp16)a; r[1] = (__fp16)b; return r;
#endif
}

template<int CTRL>
__device__ __forceinline__ float dppmovf(float x) {
    return __builtin_bit_cast(float,
        __builtin_amdgcn_mov_dpp(__builtin_bit_cast(int, x), CTRL, 0xf, 0xf, true));
}
template<int CTRL>
__device__ __forceinline__ float dppadd(float x) { return x + dppmovf<CTRL>(x); }

__device__ __forceinline__ float rsum16(float x) {   // over 16-lane row
    x += dppmovf<0x121>(x); x += dppmovf<0x122>(x);
    x += dppmovf<0x124>(x); x += dppmovf<0x128>(x);
    return x;
}
__device__ __forceinline__ float rmax16(float x) {
    x = fmaxf(x, dppmovf<0x121>(x)); x = fmaxf(x, dppmovf<0x122>(x));
    x = fmaxf(x, dppmovf<0x124>(x)); x = fmaxf(x, dppmovf<0x128>(x));
    return x;
}
__device__ __forceinline__ float swz_xor16(float x) {
    return __builtin_bit_cast(float,
        __builtin_amdgcn_ds_swizzle(__builtin_bit_cast(int, x), 0x401F));
}

// ---- prep: conv_w (fp32 OIHW [256][16][3][3]) -> fp16 A-frags in ws ----
// frag f = (kt*16 + m): lane l holds A[oc = m*16 + (l&15)][k = kt*32 + (l>>4)*8 + j]
__global__ __launch_bounds__(256)
void prep_wfrag(const float* __restrict__ w, __fp16* __restrict__ wf) {
    const int gid = blockIdx.x * 256 + threadIdx.x;
    if (gid >= KT * 16 * 64) return;
    const int l = gid & 63, m = (gid >> 6) & 15, kt = gid >> 10;
    const int oc = m * 16 + (l & 15);
    h2* dp = reinterpret_cast<h2*>(wf + (size_t)gid * 8);
    #pragma unroll
    for (int jw = 0; jw < 4; ++jw) {
        const int k0 = kt * 32 + (l >> 4) * 8 + jw * 2;
        float f0 = 0.f, f1 = 0.f;
        if (k0 < 144)     f0 = w[oc * 144 + (k0 & 15) * 9 + (k0 >> 4)];
        if (k0 + 1 < 144) f1 = w[oc * 144 + ((k0 + 1) & 15) * 9 + ((k0 + 1) >> 4)];
        dp[jw] = pkh(f0, f1);
    }
}

__global__ __launch_bounds__(256)
void convcaps_mfma(const float* __restrict__ x,
                   const __fp16* __restrict__ wf,
                   const float* __restrict__ biases,
                   const int* __restrict__ routings_p,
                   float* __restrict__ out)
{
    const int t    = threadIdx.x;
    const int lane = t & 63;
    const int wv   = t >> 6;          // wave = ntile
    const int g    = lane >> 4;       // 0..3
    const int nl   = lane & 15;
    const int n    = wv * 16 + nl;    // 0..63 = p*8 + ci
    const int p_   = n >> 3, ci_ = n & 7;
    const int gh   = g >> 1;          // r9 = 2*kt + gh
    const int ql   = (g & 1) * 4;     // q base for B-frag

    const int blk  = (blockIdx.x & 7) * 512 + (blockIdx.x >> 3);
    const int wseg = blk & 7;
    const int ho   = (blk >> 3) & 63;
    const int b    = blk >> 9;
    const int wo0  = wseg * TP;
    const int routings = routings_p[0];

    __shared__ float  shu[2560];              // 10240 B: xs, then vjlds
    __shared__ float  bb[64 * 17];            // 4352 B bij [n][co] pad 17
    __shared__ float  ccl[64 * 20];           // 5120 B cij [n][co] pad 20
    __shared__ float  bl[256];                // biases
    __fp16* xs    = reinterpret_cast<__fp16*>(shu);   // 8*XCIS = 4672 halfs
    float*  vjlds = shu;                              // 2560 floats after GEMM

    // ---- stage raw x patch (fp32 -> fp16 pairs), biases, bij init ----
    for (int u = t; u < CI * 3 * NQ * 10; u += 256) {
        int c = u % 10, rem = u / 10;
        int q = rem % NQ; rem /= NQ;
        int r = rem % 3, ci = rem / 3;
        int hy = ho - 1 + r, wx = wo0 - 1 + c;
        float f0 = 0.f, f1 = 0.f;
        if (hy >= 0 && hy < H && wx >= 0 && wx < Wd) {
            const float* xp = x + (((size_t)(b * CI + ci) * PIn + 2 * q) * H + hy) * Wd + wx;
            f0 = xp[0]; f1 = xp[H * Wd];
        }
        *reinterpret_cast<h2*>(&xs[ci * XCIS + (r * NQ + q) * RS + 2 * c]) = pkh(f0, f1);
    }
    bl[t] = biases[t];
    for (int i = t; i < 64 * 17; i += 256) bb[i] = 0.f;
    __syncthreads();

    // ---- GEMM: acc[m] = votes[oc = m*16+g*4+r][n]; B read direct from xs ----
    f32x4 acc[16];
    #pragma unroll
    for (int m = 0; m < 16; ++m) acc[m] = f32x4{0.f, 0.f, 0.f, 0.f};

    const f16x8* ap = reinterpret_cast<const f16x8*>(wf);
    #pragma unroll
    for (int kt = 0; kt < KT; ++kt) {
        f16x8 bfrag;
        const int k0 = kt * 32 + g * 8;
        if (k0 < 144) {
            const int r9 = 2 * kt + gh;
            const int kh = (r9 * 11) >> 5;        // r9/3 for r9<=9
            const int kw = r9 - 3 * kh;
            const __fp16* rp = &xs[ci_ * XCIS + (kh * NQ + ql) * RS + 2 * (p_ + kw)];
            h2 b0 = *reinterpret_cast<const h2*>(rp);
            h2 b1 = *reinterpret_cast<const h2*>(rp + RS);
            h2 b2 = *reinterpret_cast<const h2*>(rp + 2 * RS);
            h2 b3 = *reinterpret_cast<const h2*>(rp + 3 * RS);
            bfrag = f16x8{b0[0], b0[1], b1[0], b1[1], b2[0], b2[1], b3[0], b3[1]};
        } else {
            bfrag = f16x8{(__fp16)0.f, (__fp16)0.f, (__fp16)0.f, (__fp16)0.f,
                          (__fp16)0.f, (__fp16)0.f, (__fp16)0.f, (__fp16)0.f};
        }
        #pragma unroll
        for (int m = 0; m < 16; ++m) {
            const f16x8 afrag = ap[(kt * 16 + m) * 64 + lane];
            acc[m] = __builtin_amdgcn_mfma_f32_16x16x32_f16(afrag, bfrag, acc[m], 0, 0, 0);
        }
    }
    __syncthreads();   // xs dead; shu becomes vjlds

    // ---- routing in MFMA layout ----
    for (int it = 0; it < routings; ++it) {
        // softmax over co: 1024 items, item i -> row=i>>4 (= n), co=i&15
        #pragma unroll
        for (int k2 = 0; k2 < 4; ++k2) {
            const int i   = t + 256 * k2;
            const int row = i >> 4;
            const float bv = bb[row * 17 + (i & 15)];
            const float mx = rmax16(bv);
            const float e  = __expf(bv - mx);
            const float sd = rsum16(e);
            ccl[row * 20 + (i & 15)] = e * __builtin_amdgcn_rcpf(sd);
        }
        __syncthreads();

        const bool lastit = (it + 1 >= routings);
        #pragma unroll
        for (int m = 0; m < 16; ++m) {
            const float cw = ccl[n * 20 + m];
            float s0 = cw * acc[m][0], s1 = cw * acc[m][1];
            float s2 = cw * acc[m][2], s3 = cw * acc[m][3];
            // sum over ci (lane bits 0..2): xor1, xor2, xor7
            s0 = dppadd<0xB1>(s0);  s1 = dppadd<0xB1>(s1);
            s2 = dppadd<0xB1>(s2);  s3 = dppadd<0xB1>(s3);
            s0 = dppadd<0x4E>(s0);  s1 = dppadd<0x4E>(s1);
            s2 = dppadd<0x4E>(s2);  s3 = dppadd<0x4E>(s3);
            s0 = dppadd<0x141>(s0); s1 = dppadd<0x141>(s1);
            s2 = dppadd<0x141>(s2); s3 = dppadd<0x141>(s3);
            const f32x4 b4 = *reinterpret_cast<const f32x4*>(&bl[m * 16 + g * 4]);
            s0 += b4[0]; s1 += b4[1]; s2 += b4[2]; s3 += b4[3];
            // squash: n2 over po = 4 local r + lanes l^16, l^32
            float q2 = s0 * s0 + s1 * s1 + s2 * s2 + s3 * s3;
            q2 += swz_xor16(q2);
            q2 += __shfl_xor(q2, 32, 64);
            const float sc = __fsqrt_rn(q2) * __builtin_amdgcn_rcpf(1.f + q2);
            const float v0 = s0 * sc, v1 = s1 * sc, v2 = s2 * sc, v3 = s3 * sc;
            if (!lastit) {
                float uu = acc[m][0] * v0 + acc[m][1] * v1
                         + acc[m][2] * v2 + acc[m][3] * v3;
                uu += swz_xor16(uu);
                uu += __shfl_xor(uu, 32, 64);
                if (g == 0) bb[n * 17 + m] += uu;
            } else if (ci_ == 0) {
                const int oc = m * 16 + g * 4;
                vjlds[(oc + 0) * 10 + p_] = v0;
                vjlds[(oc + 1) * 10 + p_] = v1;
                vjlds[(oc + 2) * 10 + p_] = v2;
                vjlds[(oc + 3) * 10 + p_] = v3;
            }
        }
        __syncthreads();
    }

    // ---- dense output: thread t = oc, 8 wo ----
    float o[8];
    #pragma unroll
    for (int j = 0; j < 8; ++j) o[j] = vjlds[t * 10 + j];
    float* op = out + ((size_t)(b * 256 + t)) * (H * Wd) + ho * Wd + wo0;
    *reinterpret_cast<float4*>(op)     = make_float4(o[0], o[1], o[2], o[3]);
    *reinterpret_cast<float4*>(op + 4) = make_float4(o[4], o[5], o[6], o[7]);
}

extern "C" void kernel_launch(void* const* d_in, const int* in_sizes, int n_in,
                              void* d_out, int out_size, void* d_ws, size_t ws_size,
                              hipStream_t stream) {
    const float* x       = (const float*)d_in[0];
    const float* w       = (const float*)d_in[1];
    const float* biases  = (const float*)d_in[2];
    const int*   routing = (const int*)d_in[3];
    float* out = (float*)d_out;
    __fp16* wf = (__fp16*)d_ws;   // needs 81920 B

    hipLaunchKernelGGL(prep_wfrag, dim3(20), dim3(256), 0, stream, w, wf);
    hipLaunchKernelGGL(convcaps_mfma, dim3(8 * 64 * (64 / TP)), dim3(256), 0, stream,
                       x, wf, biases, routing, out);
}

// Round 7
// 136.649 us; speedup vs baseline: 1.4224x; 1.4224x over previous
//
#include <hip/hip_runtime.h>

// ConvCaps via MFMA: per block (b, ho, 8 wo), votes = W[256 oc x 144 k] *
// X_im2col[144 k x 64 n], n = p*8+ci, k = (kh*3+kw)*16 + pi (padded to 160).
// mfma_f32_16x16x32_f16, fp32 accumulate. Prep kernel writes fp16 A-frags
// (80 KB) to d_ws once per call; all blocks stream them from L2.
// B-frag = ONE aligned ds_read_b128 from xs: layout xs[ci][r][c][q] (q = pi
// pair innermost, h2 units), per-ci stride 244 words (%32=20 -> 8 ci lanes
// hit 8 distinct banks). A frag's 8 k's share one (kh,kw) since
// k0 = kt*32+g*8 is 0 or 8 mod 16.
// Routing runs in MFMA C-layout: lane=(p,ci), regs=[co=m][po=g*4+r].
//   ci-sum   : DPP quad_perm xor1 (0xB1), xor2 (0x4E), row xor7-rotate (0x141)
//   po-sum   : ds_swizzle xor16 (0x401F) + __shfl_xor 32
//   softmax  : 1024 items over 256 threads, DPP row_ror reduces
// bb stride 17 (16 writer lanes -> 16 banks). vjlds unions with dead xs.

namespace {
constexpr int CI = 8, PIn = 16, H = 64, Wd = 64;
constexpr int TP = 8;          // wo pixels per block
constexpr int NQ = 8;          // pi pairs in x patch
constexpr int CIW = 244;       // per-ci stride in words (3*10*8=240 + 4 pad)
constexpr int KT = 5;          // K tiles of 32 (K=160, 144 real)
}

typedef __fp16 h2  __attribute__((ext_vector_type(2)));
typedef __fp16 f16x8 __attribute__((ext_vector_type(8)));
typedef float  f32x4 __attribute__((ext_vector_type(4)));

__device__ __forceinline__ h2 pkh(float a, float b) {
#if __has_builtin(__builtin_amdgcn_cvt_pkrtz)
    return __builtin_amdgcn_cvt_pkrtz(a, b);
#else
    h2 r; r[0] = (__fp16)a; r[1] = (__fp16)b; return r;
#endif
}

template<int CTRL>
__device__ __forceinline__ float dppmovf(float x) {
    return __builtin_bit_cast(float,
        __builtin_amdgcn_mov_dpp(__builtin_bit_cast(int, x), CTRL, 0xf, 0xf, true));
}
template<int CTRL>
__device__ __forceinline__ float dppadd(float x) { return x + dppmovf<CTRL>(x); }

__device__ __forceinline__ float rsum16(float x) {   // over 16-lane row
    x += dppmovf<0x121>(x); x += dppmovf<0x122>(x);
    x += dppmovf<0x124>(x); x += dppmovf<0x128>(x);
    return x;
}
__device__ __forceinline__ float rmax16(float x) {
    x = fmaxf(x, dppmovf<0x121>(x)); x = fmaxf(x, dppmovf<0x122>(x));
    x = fmaxf(x, dppmovf<0x124>(x)); x = fmaxf(x, dppmovf<0x128>(x));
    return x;
}
__device__ __forceinline__ float swz_xor16(float x) {
    return __builtin_bit_cast(float,
        __builtin_amdgcn_ds_swizzle(__builtin_bit_cast(int, x), 0x401F));
}

// ---- prep: conv_w (fp32 OIHW [256][16][3][3]) -> fp16 A-frags in ws ----
// frag f = (kt*16 + m): lane l holds A[oc = m*16 + (l&15)][k = kt*32 + (l>>4)*8 + j]
__global__ __launch_bounds__(256)
void prep_wfrag(const float* __restrict__ w, __fp16* __restrict__ wf) {
    const int gid = blockIdx.x * 256 + threadIdx.x;
    if (gid >= KT * 16 * 64) return;
    const int l = gid & 63, m = (gid >> 6) & 15, kt = gid >> 10;
    const int oc = m * 16 + (l & 15);
    h2* dp = reinterpret_cast<h2*>(wf + (size_t)gid * 8);
    #pragma unroll
    for (int jw = 0; jw < 4; ++jw) {
        const int k0 = kt * 32 + (l >> 4) * 8 + jw * 2;
        float f0 = 0.f, f1 = 0.f;
        if (k0 < 144)     f0 = w[oc * 144 + (k0 & 15) * 9 + (k0 >> 4)];
        if (k0 + 1 < 144) f1 = w[oc * 144 + ((k0 + 1) & 15) * 9 + ((k0 + 1) >> 4)];
        dp[jw] = pkh(f0, f1);
    }
}

__global__ __launch_bounds__(256, 5)
void convcaps_mfma(const float* __restrict__ x,
                   const __fp16* __restrict__ wf,
                   const float* __restrict__ biases,
                   const int* __restrict__ routings_p,
                   float* __restrict__ out)
{
    const int t    = threadIdx.x;
    const int lane = t & 63;
    const int wv   = t >> 6;          // wave = ntile
    const int g    = lane >> 4;       // 0..3
    const int nl   = lane & 15;
    const int n    = wv * 16 + nl;    // 0..63 = p*8 + ci
    const int p_   = n >> 3, ci_ = n & 7;
    const int gh   = g >> 1;          // r9 = 2*kt + gh
    const int ql   = (g & 1) * 4;     // q base for B-frag

    const int blk  = (blockIdx.x & 7) * 512 + (blockIdx.x >> 3);
    const int wseg = blk & 7;
    const int ho   = (blk >> 3) & 63;
    const int b    = blk >> 9;
    const int wo0  = wseg * TP;
    const int routings = routings_p[0];

    __shared__ float  shu[2560];              // 10240 B: xs (7808 B), then vjlds
    __shared__ float  bb[64 * 17];            // 4352 B bij [n][co] pad 17
    __shared__ float  ccl[64 * 20];           // 5120 B cij [n][co] pad 20
    __shared__ float  bl[256];                // biases
    h2*    xs    = reinterpret_cast<h2*>(shu);     // [ci][r][c][q], CIW words/ci
    float* vjlds = shu;                            // 2560 floats after GEMM

    // ---- stage raw x patch (fp32 -> fp16 pairs), biases, bij init ----
    // unit u = (ci, r, q, c): c fastest for coalesced-ish global gather
    for (int u = t; u < CI * 3 * NQ * 10; u += 256) {
        int c = u % 10, rem = u / 10;
        int q = rem % NQ; rem /= NQ;
        int r = rem % 3, ci = rem / 3;
        int hy = ho - 1 + r, wx = wo0 - 1 + c;
        float f0 = 0.f, f1 = 0.f;
        if (hy >= 0 && hy < H && wx >= 0 && wx < Wd) {
            const float* xp = x + (((size_t)(b * CI + ci) * PIn + 2 * q) * H + hy) * Wd + wx;
            f0 = xp[0]; f1 = xp[H * Wd];
        }
        xs[ci * CIW + (r * 10 + c) * 8 + q] = pkh(f0, f1);
    }
    bl[t] = biases[t];
    for (int i = t; i < 64 * 17; i += 256) bb[i] = 0.f;
    __syncthreads();

    // ---- GEMM: acc[m] = votes[oc = m*16+g*4+r][n]; B = one b128 from xs ----
    f32x4 acc[16];
    #pragma unroll
    for (int m = 0; m < 16; ++m) acc[m] = f32x4{0.f, 0.f, 0.f, 0.f};

    const f16x8* ap = reinterpret_cast<const f16x8*>(wf);
    #pragma unroll
    for (int kt = 0; kt < KT; ++kt) {
        f16x8 bfrag;
        const int k0 = kt * 32 + g * 8;
        if (k0 < 144) {
            const int r9 = 2 * kt + gh;
            const int kh = (r9 * 11) >> 5;        // r9/3 for r9<=8
            const int kw = r9 - 3 * kh;
            bfrag = *reinterpret_cast<const f16x8*>(
                &xs[ci_ * CIW + (kh * 10 + p_ + kw) * 8 + ql]);
        } else {
            bfrag = f16x8{(__fp16)0.f, (__fp16)0.f, (__fp16)0.f, (__fp16)0.f,
                          (__fp16)0.f, (__fp16)0.f, (__fp16)0.f, (__fp16)0.f};
        }
        #pragma unroll
        for (int m = 0; m < 16; ++m) {
            const f16x8 afrag = ap[(kt * 16 + m) * 64 + lane];
            acc[m] = __builtin_amdgcn_mfma_f32_16x16x32_f16(afrag, bfrag, acc[m], 0, 0, 0);
        }
    }
    __syncthreads();   // xs dead; shu becomes vjlds

    // ---- routing in MFMA layout ----
    for (int it = 0; it < routings; ++it) {
        // softmax over co: 1024 items, item i -> row=i>>4 (= n), co=i&15
        #pragma unroll
        for (int k2 = 0; k2 < 4; ++k2) {
            const int i   = t + 256 * k2;
            const int row = i >> 4;
            const float bv = bb[row * 17 + (i & 15)];
            const float mx = rmax16(bv);
            const float e  = __expf(bv - mx);
            const float sd = rsum16(e);
            ccl[row * 20 + (i & 15)] = e * __builtin_amdgcn_rcpf(sd);
        }
        __syncthreads();

        const bool lastit = (it + 1 >= routings);
        #pragma unroll
        for (int m = 0; m < 16; ++m) {
            const float cw = ccl[n * 20 + m];
            float s0 = cw * acc[m][0], s1 = cw * acc[m][1];
            float s2 = cw * acc[m][2], s3 = cw * acc[m][3];
            // sum over ci (lane bits 0..2): xor1, xor2, xor7
            s0 = dppadd<0xB1>(s0);  s1 = dppadd<0xB1>(s1);
            s2 = dppadd<0xB1>(s2);  s3 = dppadd<0xB1>(s3);
            s0 = dppadd<0x4E>(s0);  s1 = dppadd<0x4E>(s1);
            s2 = dppadd<0x4E>(s2);  s3 = dppadd<0x4E>(s3);
            s0 = dppadd<0x141>(s0); s1 = dppadd<0x141>(s1);
            s2 = dppadd<0x141>(s2); s3 = dppadd<0x141>(s3);
            const f32x4 b4 = *reinterpret_cast<const f32x4*>(&bl[m * 16 + g * 4]);
            s0 += b4[0]; s1 += b4[1]; s2 += b4[2]; s3 += b4[3];
            // squash: n2 over po = 4 local r + lanes l^16, l^32
            float q2 = s0 * s0 + s1 * s1 + s2 * s2 + s3 * s3;
            q2 += swz_xor16(q2);
            q2 += __shfl_xor(q2, 32, 64);
            const float sc = __fsqrt_rn(q2) * __builtin_amdgcn_rcpf(1.f + q2);
            const float v0 = s0 * sc, v1 = s1 * sc, v2 = s2 * sc, v3 = s3 * sc;
            if (!lastit) {
                float uu = acc[m][0] * v0 + acc[m][1] * v1
                         + acc[m][2] * v2 + acc[m][3] * v3;
                uu += swz_xor16(uu);
                uu += __shfl_xor(uu, 32, 64);
                if (g == 0) bb[n * 17 + m] += uu;
            } else if (ci_ == 0) {
                const int oc = m * 16 + g * 4;
                vjlds[(oc + 0) * 10 + p_] = v0;
                vjlds[(oc + 1) * 10 + p_] = v1;
                vjlds[(oc + 2) * 10 + p_] = v2;
                vjlds[(oc + 3) * 10 + p_] = v3;
            }
        }
        __syncthreads();
    }

    // ---- dense output: thread t = oc, 8 wo ----
    float o[8];
    #pragma unroll
    for (int j = 0; j < 8; ++j) o[j] = vjlds[t * 10 + j];
    float* op = out + ((size_t)(b * 256 + t)) * (H * Wd) + ho * Wd + wo0;
    *reinterpret_cast<float4*>(op)     = make_float4(o[0], o[1], o[2], o[3]);
    *reinterpret_cast<float4*>(op + 4) = make_float4(o[4], o[5], o[6], o[7]);
}

extern "C" void kernel_launch(void* const* d_in, const int* in_sizes, int n_in,
                              void* d_out, int out_size, void* d_ws, size_t ws_size,
                              hipStream_t stream) {
    const float* x       = (const float*)d_in[0];
    const float* w       = (const float*)d_in[1];
    const float* biases  = (const float*)d_in[2];
    const int*   routing = (const int*)d_in[3];
    float* out = (float*)d_out;
    __fp16* wf = (__fp16*)d_ws;   // needs 81920 B

    hipLaunchKernelGGL(prep_wfrag, dim3(20), dim3(256), 0, stream, w, wf);
    hipLaunchKernelGGL(convcaps_mfma, dim3(8 * 64 * (64 / TP)), dim3(256), 0, stream,
                       x, wf, biases, routing, out);
}